// Round 1
// baseline (187.493 us; speedup 1.0000x reference)
//
#include <hip/hip_runtime.h>

// Profile-HMM forward (log2-domain) + KLD, MI355X.
// One wave (64 lanes) per batch element; lane i owns states k=2i+1, 2i+2.
// Delete-chain solved per column with a segmented Kogge-Stone shuffle scan.

constexpr float LOG2E = 1.4426950408889634f;
constexpr float LN2   = 0.6931471805599453f;
constexpr float NEG2  = -100.0f * 1.4426950408889634f; // NEG in log2 units
constexpr float LQ2   = -2.0f;                         // log2(0.25)

__device__ __forceinline__ float exp2_hw(float x) {
    float r; asm("v_exp_f32 %0, %1" : "=v"(r) : "v"(x)); return r;
}
__device__ __forceinline__ float log2_hw(float x) {
    float r; asm("v_log_f32 %0, %1" : "=v"(r) : "v"(x)); return r;
}
// log2(2^x + 2^y)
__device__ __forceinline__ float lae2(float x, float y) {
    float m = fmaxf(x, y);
    float e = exp2_hw(-fabsf(x - y));
    return m + log2_hw(1.0f + e);
}
// log2(2^p + 2^q + 2^r)
__device__ __forceinline__ float lse3_2(float p, float q, float r) {
    float m = fmaxf(fmaxf(p, q), r);
    float s = exp2_hw(p - m) + exp2_hw(q - m) + exp2_hw(r - m);
    return m + log2_hw(s);
}

// transitions: (B, 129, 7)  M2M=0 M2I=1 M2D=2 I2M=3 I2I=4 D2M=5 D2D=6
// emissions:   (B, 128, 4)
// tokens:      (B, 256) int32 in [0,4)
__global__ __launch_bounds__(64) void phmm_fwd(const int* __restrict__ tokens,
                                               const float* __restrict__ trans,
                                               const float* __restrict__ emis,
                                               float* __restrict__ nll_out)
{
    const int b = blockIdx.x;
    const int i = threadIdx.x; // lane: k1 = 2i+1, k2 = 2i+2

    const float* ab = trans + (size_t)b * (129 * 7);
    const int r0 = (2 * i) * 7, r1 = (2 * i + 1) * 7, r2 = (2 * i + 2) * 7;

    // row 2i: feeds fM_new[k1] and D-chain (x,c) at k1
    const float aM2M0 = ab[r0 + 0] * LOG2E, aI2M0 = ab[r0 + 3] * LOG2E, aD2M0 = ab[r0 + 5] * LOG2E;
    const float aM2D0 = ab[r0 + 2] * LOG2E, aD2D0 = ab[r0 + 6] * LOG2E;
    // row 2i+1: feeds fM_new[k2], D-chain at k2, fI_new[k1]
    const float aM2M1 = ab[r1 + 0] * LOG2E, aI2M1 = ab[r1 + 3] * LOG2E, aD2M1 = ab[r1 + 5] * LOG2E;
    const float aM2D1 = ab[r1 + 2] * LOG2E, aD2D1 = ab[r1 + 6] * LOG2E;
    const float aM2I1 = ab[r1 + 1] * LOG2E, aI2I1 = ab[r1 + 4] * LOG2E;
    // row 2i+2: feeds fI_new[k2]
    const float aM2I2 = ab[r2 + 1] * LOG2E, aI2I2 = ab[r2 + 4] * LOG2E;
    // row 0 (broadcast): fI_new[0]
    const float a0M2I = ab[1] * LOG2E, a0I2I = ab[4] * LOG2E;
    // row K=128 (broadcast): final reduction (lane 63's state is k=128)
    const float aKM2M = ab[128 * 7 + 0] * LOG2E, aKI2M = ab[128 * 7 + 3] * LOG2E,
                aKD2M = ab[128 * 7 + 5] * LOG2E;

    const float4* eb = (const float4*)(emis + (size_t)b * 512);
    float4 em1 = eb[2 * i];
    float4 em2 = eb[2 * i + 1];
    em1.x *= LOG2E; em1.y *= LOG2E; em1.z *= LOG2E; em1.w *= LOG2E;
    em2.x *= LOG2E; em2.y *= LOG2E; em2.z *= LOG2E; em2.w *= LOG2E;

    const int4 tok = ((const int4*)(tokens + (size_t)b * 256))[i]; // t = 4i..4i+3

    // DP state (log2 units)
    float fM0 = 0.0f, fI0 = NEG2;
    float fM1 = NEG2, fM2 = NEG2;
    float fI1 = NEG2, fI2 = NEG2;
    float fD1, fD2; // fD0 == NEG2 always

    // Delete-chain: fD[k] = lae2(aM2D[k-1] + fM[k-1], aD2D[k-1] + fD[k-1]), fD[0]=NEG.
    // Segmented Kogge-Stone scan: segment (A,C) means out = lae2(A, C + in).
    auto dscan = [&](float m0, float m1, float m2, float& D1, float& D2) {
        float mp = __shfl_up(m2, 1);
        if (i == 0) mp = m0;
        float x1 = aM2D0 + mp;  // x at k1 = 2i+1
        float x2 = aM2D1 + m1;  // x at k2 = 2i+2
        float A = lae2(x2, aD2D1 + x1); // local combine of (x1,c1)∘(x2,c2)
        float C = aD2D0 + aD2D1;
        #pragma unroll
        for (int d = 1; d < 64; d <<= 1) {
            float Ao = __shfl_up(A, d);
            float Co = __shfl_up(C, d);
            float An = lae2(A, C + Ao);
            float Cn = C + Co;
            if (i >= d) { A = An; C = Cn; }
        }
        float Ae = __shfl_up(A, 1);
        float Ce = __shfl_up(C, 1);
        float din = (i == 0) ? NEG2 : lae2(Ae, Ce + NEG2); // fD[2i]
        D1 = lae2(x1, aD2D0 + din);
        D2 = lae2(x2, aD2D1 + D1);
    };

    dscan(fM0, fM1, fM2, fD1, fD2); // initial fD from initial fM (fM[0]=0)

    #pragma unroll 1
    for (int t4 = 0; t4 < 64; ++t4) {
        const int sx = __shfl(tok.x, t4);
        const int sy = __shfl(tok.y, t4);
        const int sz = __shfl(tok.z, t4);
        const int sw = __shfl(tok.w, t4);
        #pragma unroll
        for (int j = 0; j < 4; ++j) {
            const int sym = (j == 0) ? sx : (j == 1) ? sy : (j == 2) ? sz : sw;
            // emission select (sym is wave-uniform)
            const float e1 = (sym & 2) ? ((sym & 1) ? em1.w : em1.z)
                                       : ((sym & 1) ? em1.y : em1.x);
            const float e2 = (sym & 2) ? ((sym & 1) ? em2.w : em2.z)
                                       : ((sym & 1) ? em2.y : em2.x);
            // neighbor (k-1) old state for k1 (lane i-1's k2 == 2i)
            float fMp = __shfl_up(fM2, 1);
            float fIp = __shfl_up(fI2, 1);
            float fDp = __shfl_up(fD2, 1);
            if (i == 0) { fMp = fM0; fIp = fI0; fDp = NEG2; }

            const float nM1 = e1 + lse3_2(aM2M0 + fMp, aI2M0 + fIp, aD2M0 + fDp);
            const float nM2 = e2 + lse3_2(aM2M1 + fM1, aI2M1 + fI1, aD2M1 + fD1);
            const float nI0 = LQ2 + lae2(a0M2I + fM0, a0I2I + fI0);
            const float nI1 = LQ2 + lae2(aM2I1 + fM1, aI2I1 + fI1);
            const float nI2 = LQ2 + lae2(aM2I2 + fM2, aI2I2 + fI2);

            fM0 = NEG2; fI0 = nI0;
            fM1 = nM1;  fM2 = nM2;
            fI1 = nI1;  fI2 = nI2;
            dscan(NEG2, fM1, fM2, fD1, fD2); // fM_new[0] == NEG
        }
    }

    const float fin = lse3_2(fM2 + aKM2M, fI2 + aKI2M, fD2 + aKD2M);
    if (i == 63) nll_out[b] = -fin * LN2; // back to natural-log units
}

__global__ __launch_bounds__(256) void phmm_finish(const float* __restrict__ nll,
                                                   const float* __restrict__ mus,
                                                   const float* __restrict__ logvars,
                                                   float* __restrict__ out)
{
    const int tid = threadIdx.x;
    float acc = 0.0f;
    for (int idx = tid; idx < 512; idx += 256) acc += nll[idx];
    for (int idx = tid; idx < 8192; idx += 256) {
        const float mu = mus[idx], lv = logvars[idx];
        acc -= 0.5f * (1.0f + lv - mu * mu - exp2_hw(lv * LOG2E));
    }
    #pragma unroll
    for (int off = 32; off >= 1; off >>= 1) acc += __shfl_down(acc, off);
    __shared__ float red[4];
    if ((tid & 63) == 0) red[tid >> 6] = acc;
    __syncthreads();
    if (tid == 0) out[0] = (red[0] + red[1] + red[2] + red[3]) * (1.0f / 512.0f);
}

extern "C" void kernel_launch(void* const* d_in, const int* in_sizes, int n_in,
                              void* d_out, int out_size, void* d_ws, size_t ws_size,
                              hipStream_t stream)
{
    const int*   tokens  = (const int*)d_in[0];   // (512, 256) int32
    const float* trans   = (const float*)d_in[1]; // (512, 129, 7) f32
    const float* emis    = (const float*)d_in[2]; // (512, 128, 4) f32
    const float* mus     = (const float*)d_in[3]; // (512, 16) f32
    const float* logvars = (const float*)d_in[4]; // (512, 16) f32
    float* nll = (float*)d_ws;                    // 512 floats scratch

    phmm_fwd<<<dim3(512), dim3(64), 0, stream>>>(tokens, trans, emis, nll);
    phmm_finish<<<dim3(1), dim3(256), 0, stream>>>(nll, mus, logvars, (float*)d_out);
}

// Round 2
// 99.948 us; speedup vs baseline: 1.8759x; 1.8759x over previous
//
#include <hip/hip_runtime.h>

// Profile-HMM forward (log2-domain) + KLD, MI355X.
// One wave per batch element; lane i owns states k1=2i+1, k2=2i+2.
// Wavefront/skewed schedule: at step s, lane i computes COLUMN c = s - i.
// The delete-chain (serial in k within a column) becomes a 1-lane-hop
// pipeline: fD_new[2i] arrives from lane i-1's previous step via shfl_up.

constexpr float LOG2E = 1.4426950408889634f;
constexpr float LN2   = 0.6931471805599453f;
constexpr float NEG2  = -100.0f * 1.4426950408889634f; // NEG in log2 units
constexpr float LQ2   = -2.0f;                         // log2(0.25)

__device__ __forceinline__ float exp2_hw(float x) {
    float r; asm("v_exp_f32 %0, %1" : "=v"(r) : "v"(x)); return r;
}
__device__ __forceinline__ float log2_hw(float x) {
    float r; asm("v_log_f32 %0, %1" : "=v"(r) : "v"(x)); return r;
}
// log2(2^x + 2^y)
__device__ __forceinline__ float lae2(float x, float y) {
    float m = fmaxf(x, y);
    float e = exp2_hw(-fabsf(x - y));
    return m + log2_hw(1.0f + e);
}
// log2(2^p + 2^q + 2^r)
__device__ __forceinline__ float lse3_2(float p, float q, float r) {
    float m = fmaxf(fmaxf(p, q), r);
    float s = exp2_hw(p - m) + exp2_hw(q - m) + exp2_hw(r - m);
    return m + log2_hw(s);
}

// Per-step update. S: step index (uniform). FRESH: token[S-1] broadcast (for lane 0).
// MODE 0: fill (init + activity masks, c>=1 test). MODE 1: steady (no masks).
// MODE 2: drain (c<=256 test).
#define STEP(S, FRESH, MODE) do {                                              \
    float nbM = __shfl_up(dM2, 1);  /* fM[2i]   @ col c-1 */                   \
    float nbI = __shfl_up(dI2, 1);  /* fI[2i]   @ col c-1 */                   \
    float nbD = __shfl_up(dD2, 1);  /* fD[2i]   @ col c-1 */                   \
    float nwM = __shfl_up(cM2, 1);  /* fM_new[2i] @ col c */                   \
    float nwD = __shfl_up(cD2, 1);  /* fD_new[2i] @ col c */                   \
    int   tup = __shfl_up(tok, 1);                                             \
    if (i == 0) { nbM = fM0; nbI = fI0; nbD = NEG2;                            \
                  nwM = NEG2; nwD = NEG2; tup = (FRESH); }                     \
    tok = tup;                                                                 \
    const int sym = tok;                                                       \
    float lo1 = (sym & 1) ? em1.y : em1.x, hi1 = (sym & 1) ? em1.w : em1.z;    \
    float e1  = (sym & 2) ? hi1 : lo1;                                         \
    float lo2 = (sym & 1) ? em2.y : em2.x, hi2 = (sym & 1) ? em2.w : em2.z;    \
    float e2  = (sym & 2) ? hi2 : lo2;                                         \
    float nM1 = e1 + lse3_2(aM2M0 + nbM, aI2M0 + nbI, aD2M0 + nbD);            \
    float nM2 = e2 + lse3_2(aM2M1 + cM1, aI2M1 + cI1, aD2M1 + cD1);            \
    float nI1 = lae2(aM2I1 + cM1, aI2I1 + cI1);  /* LQ2 pre-folded */          \
    float nI2 = lae2(aM2I2 + cM2, aI2I2 + cI2);                                \
    float nD1 = lae2(aM2D0 + nwM, aD2D0 + nwD);                                \
    float nD2 = lae2(aM2D1 + nM1, aD2D1 + nD1);                                \
    float nI0v = lae2(a0M2I + fM0, a0I2I + fI0);                               \
    dM2 = cM2; dI2 = cI2; dD2 = cD2;                                           \
    if ((MODE) == 1) {                                                         \
        cM1 = nM1; cM2 = nM2; cI1 = nI1; cI2 = nI2; cD1 = nD1; cD2 = nD2;      \
    } else if ((MODE) == 0) {                                                  \
        const int c = (S) - i;                                                 \
        const bool act = (c >= 1);                                             \
        const bool ini = (c == 0);                                             \
        float iD1 = lae2(aM2D0 + NEG2, aD2D0 + nwD); /* col-0 D init */        \
        float iD2 = lae2(aM2D1 + NEG2, aD2D1 + iD1);                           \
        cM1 = act ? nM1 : cM1; cM2 = act ? nM2 : cM2;                          \
        cI1 = act ? nI1 : cI1; cI2 = act ? nI2 : cI2;                          \
        cD1 = act ? nD1 : (ini ? iD1 : cD1);                                   \
        cD2 = act ? nD2 : (ini ? iD2 : cD2);                                   \
    } else {                                                                   \
        const int c = (S) - i;                                                 \
        const bool act = (c <= 256);                                           \
        cM1 = act ? nM1 : cM1; cM2 = act ? nM2 : cM2;                          \
        cI1 = act ? nI1 : cI1; cI2 = act ? nI2 : cI2;                          \
        cD1 = act ? nD1 : cD1; cD2 = act ? nD2 : cD2;                          \
    }                                                                          \
    fI0 = nI0v; fM0 = NEG2; /* replicated in all lanes, wave-uniform */        \
} while (0)

// transitions: (B, 129, 7)  M2M=0 M2I=1 M2D=2 I2M=3 I2I=4 D2M=5 D2D=6
// emissions:   (B, 128, 4);  tokens: (B, 256) int32 in [0,4)
__global__ __launch_bounds__(64) void phmm_fwd(const int* __restrict__ tokens,
                                               const float* __restrict__ trans,
                                               const float* __restrict__ emis,
                                               float* __restrict__ nll_out)
{
    const int b = blockIdx.x;
    const int i = threadIdx.x;

    const float* ab = trans + (size_t)b * (129 * 7);
    const int r0 = (2 * i) * 7, r1 = (2 * i + 1) * 7, r2 = (2 * i + 2) * 7;

    const float aM2M0 = ab[r0 + 0] * LOG2E, aI2M0 = ab[r0 + 3] * LOG2E, aD2M0 = ab[r0 + 5] * LOG2E;
    const float aM2D0 = ab[r0 + 2] * LOG2E, aD2D0 = ab[r0 + 6] * LOG2E;
    const float aM2M1 = ab[r1 + 0] * LOG2E, aI2M1 = ab[r1 + 3] * LOG2E, aD2M1 = ab[r1 + 5] * LOG2E;
    const float aM2D1 = ab[r1 + 2] * LOG2E, aD2D1 = ab[r1 + 6] * LOG2E;
    const float aM2I1 = ab[r1 + 1] * LOG2E + LQ2, aI2I1 = ab[r1 + 4] * LOG2E + LQ2;
    const float aM2I2 = ab[r2 + 1] * LOG2E + LQ2, aI2I2 = ab[r2 + 4] * LOG2E + LQ2;
    const float a0M2I = ab[1] * LOG2E + LQ2,      a0I2I = ab[4] * LOG2E + LQ2;
    const float aKM2M = ab[128 * 7 + 0] * LOG2E, aKI2M = ab[128 * 7 + 3] * LOG2E,
                aKD2M = ab[128 * 7 + 5] * LOG2E;

    const float4* eb = (const float4*)(emis + (size_t)b * 512);
    float4 em1 = eb[2 * i];
    float4 em2 = eb[2 * i + 1];
    em1.x *= LOG2E; em1.y *= LOG2E; em1.z *= LOG2E; em1.w *= LOG2E;
    em2.x *= LOG2E; em2.y *= LOG2E; em2.z *= LOG2E; em2.w *= LOG2E;

    const int4 tok_store = ((const int4*)(tokens + (size_t)b * 256))[i];

    // State (log2 units). cur = own column (s-1-i) after step s-1; dly = one step older (k2 triple).
    float cM1 = NEG2, cM2 = NEG2, cI1 = NEG2, cI2 = NEG2;
    float fM0 = 0.0f, fI0 = NEG2;
    // lane 0's column-0 delete chain (others initialized in-pipeline at step s==i)
    float d1_0 = lae2(aM2D0 + 0.0f, aD2D0 + NEG2);
    float d2_0 = lae2(aM2D1 + NEG2, aD2D1 + d1_0);
    float cD1 = (i == 0) ? d1_0 : NEG2;
    float cD2 = (i == 0) ? d2_0 : NEG2;
    float dM2 = NEG2, dI2 = NEG2, dD2 = NEG2;
    int tok = 0;

    // steps s = 1 .. 320; lane i active for s in [i+1, i+256]; init at s == i.
    #pragma unroll 1
    for (int u = 0; u < 16; ++u) {          // s in [1,64]: fill (init + act masks)
        const int f0 = __builtin_amdgcn_readlane(tok_store.x, u);
        const int f1 = __builtin_amdgcn_readlane(tok_store.y, u);
        const int f2 = __builtin_amdgcn_readlane(tok_store.z, u);
        const int f3 = __builtin_amdgcn_readlane(tok_store.w, u);
        const int s0 = 1 + 4 * u;
        STEP(s0 + 0, f0, 0); STEP(s0 + 1, f1, 0);
        STEP(s0 + 2, f2, 0); STEP(s0 + 3, f3, 0);
    }
    #pragma unroll 1
    for (int u = 16; u < 64; ++u) {         // s in [65,256]: steady, all lanes active
        const int f0 = __builtin_amdgcn_readlane(tok_store.x, u);
        const int f1 = __builtin_amdgcn_readlane(tok_store.y, u);
        const int f2 = __builtin_amdgcn_readlane(tok_store.z, u);
        const int f3 = __builtin_amdgcn_readlane(tok_store.w, u);
        const int s0 = 1 + 4 * u;
        STEP(s0 + 0, f0, 1); STEP(s0 + 1, f1, 1);
        STEP(s0 + 2, f2, 1); STEP(s0 + 3, f3, 1);
    }
    #pragma unroll 1
    for (int u = 64; u < 80; ++u) {         // s in [257,320]: drain
        const int s0 = 1 + 4 * u;
        STEP(s0 + 0, 0, 2); STEP(s0 + 1, 0, 2);
        STEP(s0 + 2, 0, 2); STEP(s0 + 3, 0, 2);
    }

    const float fin = lse3_2(cM2 + aKM2M, cI2 + aKI2M, cD2 + aKD2M);
    if (i == 63) nll_out[b] = -fin * LN2;
}

__global__ __launch_bounds__(256) void phmm_finish(const float* __restrict__ nll,
                                                   const float* __restrict__ mus,
                                                   const float* __restrict__ logvars,
                                                   float* __restrict__ out)
{
    const int tid = threadIdx.x;
    float acc = 0.0f;
    for (int idx = tid; idx < 512; idx += 256) acc += nll[idx];
    for (int idx = tid; idx < 8192; idx += 256) {
        const float mu = mus[idx], lv = logvars[idx];
        acc -= 0.5f * (1.0f + lv - mu * mu - exp2_hw(lv * LOG2E));
    }
    #pragma unroll
    for (int off = 32; off >= 1; off >>= 1) acc += __shfl_down(acc, off);
    __shared__ float red[4];
    if ((tid & 63) == 0) red[tid >> 6] = acc;
    __syncthreads();
    if (tid == 0) out[0] = (red[0] + red[1] + red[2] + red[3]) * (1.0f / 512.0f);
}

extern "C" void kernel_launch(void* const* d_in, const int* in_sizes, int n_in,
                              void* d_out, int out_size, void* d_ws, size_t ws_size,
                              hipStream_t stream)
{
    const int*   tokens  = (const int*)d_in[0];   // (512, 256) int32
    const float* trans   = (const float*)d_in[1]; // (512, 129, 7) f32
    const float* emis    = (const float*)d_in[2]; // (512, 128, 4) f32
    const float* mus     = (const float*)d_in[3]; // (512, 16) f32
    const float* logvars = (const float*)d_in[4]; // (512, 16) f32
    float* nll = (float*)d_ws;                    // 512 floats scratch

    phmm_fwd<<<dim3(512), dim3(64), 0, stream>>>(tokens, trans, emis, nll);
    phmm_finish<<<dim3(1), dim3(256), 0, stream>>>(nll, mus, logvars, (float*)d_out);
}

// Round 3
// 97.487 us; speedup vs baseline: 1.9233x; 1.0252x over previous
//
#include <hip/hip_runtime.h>

// Profile-HMM forward (log2-domain) + KLD, MI355X.
// One wave per batch element; lane i owns states k1=2i+1, k2=2i+2.
// Wavefront/skewed schedule: at step s, lane i computes COLUMN c = s - i.
// v3: poly-log (no v_log_f32), saved-shfl neighbor values (4 bpermutes/step),
// packed-f32 pairs for the (k1,k2) M and I updates.

constexpr float LOG2E = 1.4426950408889634f;
constexpr float LN2   = 0.6931471805599453f;
constexpr float NEG2  = -100.0f * 1.4426950408889634f; // NEG in log2 units
constexpr float LQ2   = -2.0f;                         // log2(0.25)

// log2(1+e) on [0,1]: Taylor @ e=0.5, deg 5 (max err ~5e-4)
constexpr float K0 = 0.5849625007f, K1 = 0.9617966939f, K2 = -0.3205988980f,
                K3 = 0.1424883991f, K4 = -0.0712441995f, K5 = 0.0379969064f;
// log2(s) on [1,3] via v=s-2: Taylor @ s=2, deg 6 (max err ~3e-3)
constexpr float M0 = 1.0f, M1 = 0.7213475204f, M2 = -0.1803368801f,
                M3 = 0.0601122934f, M4 = -0.0225421100f, M5 = 0.0090168440f,
                M6 = -0.0037570184f;

typedef float v2f __attribute__((ext_vector_type(2)));

__device__ __forceinline__ float exp2_hw(float x) {
    float r; asm("v_exp_f32 %0, %1" : "=v"(r) : "v"(x)); return r;
}
__device__ __forceinline__ float plog1p(float e) { // log2(1+e), e in [0,1]
    float u  = e - 0.5f;
    float u2 = u * u;
    float a  = fmaf(u, K1, K0);
    float b  = fmaf(u, K3, K2);
    float c  = fmaf(u, K5, K4);
    return fmaf(u2, fmaf(u2, c, b), a);
}
__device__ __forceinline__ float lae2(float x, float y) { // log2(2^x + 2^y)
    float m = fmaxf(x, y);
    float d = x - y;
    float e = exp2_hw(fminf(d, -d)); // 2^(-|d|), modifiers fold into v_min
    return m + plog1p(e);
}
__device__ __forceinline__ float lse3(float p, float q, float r) {
    float m = fmaxf(fmaxf(p, q), r); // v_max3
    float s = exp2_hw(p - m) + exp2_hw(q - m) + exp2_hw(r - m); // in [1,3]
    float v  = s - 2.0f;
    float v2 = v * v;
    float A  = fmaf(v, M1, M0);
    float B  = fmaf(v, M3, M2);
    float C  = fmaf(v, M5, M4);
    float CD = fmaf(v2, M6, C);
    return m + fmaf(v2, fmaf(v2, CD, B), A);
}
// packed pair variants (v_pk_add/mul/fma_f32; exp2 is scalar-only)
__device__ __forceinline__ v2f lae2_pk(v2f x, v2f y) {
    v2f m; m.x = fmaxf(x.x, y.x); m.y = fmaxf(x.y, y.y);
    v2f d = x - y;
    v2f e; e.x = exp2_hw(fminf(d.x, -d.x)); e.y = exp2_hw(fminf(d.y, -d.y));
    v2f u  = e - 0.5f;
    v2f u2 = u * u;
    v2f a = u * K1 + K0;
    v2f b = u * K3 + K2;
    v2f c = u * K5 + K4;
    return m + (u2 * (u2 * c + b) + a);
}
__device__ __forceinline__ v2f lse3_pk(v2f p, v2f q, v2f r) {
    v2f m; m.x = fmaxf(fmaxf(p.x, q.x), r.x); m.y = fmaxf(fmaxf(p.y, q.y), r.y);
    v2f sp = p - m, sq = q - m, sr = r - m;
    v2f s;
    s.x = exp2_hw(sp.x) + exp2_hw(sq.x) + exp2_hw(sr.x);
    s.y = exp2_hw(sp.y) + exp2_hw(sq.y) + exp2_hw(sr.y);
    v2f v  = s - 2.0f;
    v2f v2_ = v * v;
    v2f A  = v * M1 + M0;
    v2f B  = v * M3 + M2;
    v2f C  = v * M5 + M4;
    v2f CD = v2_ * M6 + C;
    return m + (v2_ * (v2_ * CD + B) + A);
}
__device__ __forceinline__ float shup(float x, int a4) {
    return __int_as_float(__builtin_amdgcn_ds_bpermute(a4, __float_as_int(x)));
}

// Per-step update. S: step index (uniform; compile-time only in MODE 1/2 sense).
// nb* (neighbor @ col c-1) come from LAST step's saved shfl results p*;
// nw* (neighbor @ col c) come from THIS step's fresh shfls q*.
#define STEP(S, FRESH, MODE) do {                                              \
    const float qM = shup(cM2, up4);                                           \
    const float qI = shup(cI2, up4);                                           \
    const float qD = shup(cD2, up4);                                           \
    int tq = __builtin_amdgcn_ds_bpermute(up4, tok);                           \
    const bool isS1 = ((MODE) == 0) && ((S) == 1);                             \
    float nbM = pM, nbI = pI, nbD = pD;                                        \
    if (i == 0) {                                                              \
        nbM = isS1 ? 0.0f : NEG2;                                              \
        nbI = fI0; nbD = NEG2; tq = (FRESH);                                   \
    }                                                                          \
    tok = tq;                                                                  \
    const int sym = tok;                                                       \
    const float e1 = (sym & 2) ? ((sym & 1) ? em1.w : em1.z)                   \
                               : ((sym & 1) ? em1.y : em1.x);                  \
    const float e2 = (sym & 2) ? ((sym & 1) ? em2.w : em2.z)                   \
                               : ((sym & 1) ? em2.y : em2.x);                  \
    const float nwM = (i == 0) ? NEG2 : qM;                                    \
    const float nwD = (i == 0) ? NEG2 : qD;                                    \
    v2f P_, Q_, R_;                                                            \
    P_.x = aM2M0 + nbM; P_.y = aM2M1 + cM1;                                    \
    Q_.x = aI2M0 + nbI; Q_.y = aI2M1 + cI1;                                    \
    R_.x = aD2M0 + nbD; R_.y = aD2M1 + cD1;                                    \
    const v2f nMv = lse3_pk(P_, Q_, R_);                                       \
    const float nM1 = nMv.x + e1;                                              \
    const float nM2 = nMv.y + e2;                                              \
    v2f X_, Y_;                                                                \
    X_.x = aM2I1 + cM1; X_.y = aM2I2 + cM2;                                    \
    Y_.x = aI2I1 + cI1; Y_.y = aI2I2 + cI2;                                    \
    const v2f nIv = lae2_pk(X_, Y_);                                           \
    const float nD1 = lae2(aM2D0 + nwM, aD2D0 + nwD);                          \
    const float nD2 = lae2(aM2D1 + nM1, aD2D1 + nD1);                          \
    const float nI0v = lae2(isS1 ? A0 : A0p, B0 + fI0);                        \
    if ((MODE) == 1) {                                                         \
        cM1 = nM1; cM2 = nM2; cI1 = nIv.x; cI2 = nIv.y; cD1 = nD1; cD2 = nD2;  \
    } else if ((MODE) == 0) {                                                  \
        const int c = (S) - i;                                                 \
        const bool act = (c >= 1), actD = (c >= 0);                            \
        cM1 = act  ? nM1   : cM1; cM2 = act  ? nM2   : cM2;                    \
        cI1 = act  ? nIv.x : cI1; cI2 = act  ? nIv.y : cI2;                    \
        cD1 = actD ? nD1   : cD1; cD2 = actD ? nD2   : cD2;                    \
    } else {                                                                   \
        const int c = (S) - i;                                                 \
        const bool act = (c <= 256);                                           \
        cM1 = act ? nM1   : cM1; cM2 = act ? nM2   : cM2;                      \
        cI1 = act ? nIv.x : cI1; cI2 = act ? nIv.y : cI2;                      \
        cD1 = act ? nD1   : cD1; cD2 = act ? nD2   : cD2;                      \
    }                                                                          \
    pM = qM; pI = qI; pD = qD;                                                 \
    fI0 = nI0v;                                                                \
} while (0)

// transitions: (B, 129, 7)  M2M=0 M2I=1 M2D=2 I2M=3 I2I=4 D2M=5 D2D=6
// emissions:   (B, 128, 4);  tokens: (B, 256) int32 in [0,4)
__global__ __launch_bounds__(64) void phmm_fwd(const int* __restrict__ tokens,
                                               const float* __restrict__ trans,
                                               const float* __restrict__ emis,
                                               float* __restrict__ nll_out)
{
    const int b = blockIdx.x;
    const int i = threadIdx.x;
    const int up4 = (i - 1) * 4; // bpermute byte addr; lane0 wraps, fixed by cndmask

    const float* ab = trans + (size_t)b * (129 * 7);
    const int r0 = (2 * i) * 7, r1 = (2 * i + 1) * 7, r2 = (2 * i + 2) * 7;

    const float aM2M0 = ab[r0 + 0] * LOG2E, aI2M0 = ab[r0 + 3] * LOG2E, aD2M0 = ab[r0 + 5] * LOG2E;
    const float aM2D0 = ab[r0 + 2] * LOG2E, aD2D0 = ab[r0 + 6] * LOG2E;
    const float aM2M1 = ab[r1 + 0] * LOG2E, aI2M1 = ab[r1 + 3] * LOG2E, aD2M1 = ab[r1 + 5] * LOG2E;
    const float aM2D1 = ab[r1 + 2] * LOG2E, aD2D1 = ab[r1 + 6] * LOG2E;
    const float aM2I1 = ab[r1 + 1] * LOG2E + LQ2, aI2I1 = ab[r1 + 4] * LOG2E + LQ2;
    const float aM2I2 = ab[r2 + 1] * LOG2E + LQ2, aI2I2 = ab[r2 + 4] * LOG2E + LQ2;
    const float A0 = ab[1] * LOG2E + LQ2, B0 = ab[4] * LOG2E + LQ2;
    const float A0p = A0 + NEG2; // fM0 = NEG for columns >= 1
    const float aKM2M = ab[128 * 7 + 0] * LOG2E, aKI2M = ab[128 * 7 + 3] * LOG2E,
                aKD2M = ab[128 * 7 + 5] * LOG2E;

    const float4* eb = (const float4*)(emis + (size_t)b * 512);
    float4 em1 = eb[2 * i];
    float4 em2 = eb[2 * i + 1];
    em1.x *= LOG2E; em1.y *= LOG2E; em1.z *= LOG2E; em1.w *= LOG2E;
    em2.x *= LOG2E; em2.y *= LOG2E; em2.z *= LOG2E; em2.w *= LOG2E;

    const int4 tok_store = ((const int4*)(tokens + (size_t)b * 256))[i];

    // State (log2 units)
    float cM1 = NEG2, cM2 = NEG2, cI1 = NEG2, cI2 = NEG2;
    float pM = NEG2, pI = NEG2, pD = NEG2; // saved shfl results (neighbor col c-1)
    float fI0 = NEG2;                      // fI[0] @ current consumed column
    // lane 0's column-0 delete chain (fM[0]@col0 = 0)
    float d1_0 = lae2(aM2D0 + 0.0f, aD2D0 + NEG2);
    float d2_0 = lae2(aM2D1 + NEG2, aD2D1 + d1_0);
    float cD1 = (i == 0) ? d1_0 : NEG2;
    float cD2 = (i == 0) ? d2_0 : NEG2;
    int tok = 0;

    // steps s = 1 .. 320; lane i active for s in [i+1, i+256]; D-init at s == i.
    #pragma unroll 1
    for (int u = 0; u < 16; ++u) {          // s in [1,64]: fill
        const int f0 = __builtin_amdgcn_readlane(tok_store.x, u);
        const int f1 = __builtin_amdgcn_readlane(tok_store.y, u);
        const int f2 = __builtin_amdgcn_readlane(tok_store.z, u);
        const int f3 = __builtin_amdgcn_readlane(tok_store.w, u);
        const int s0 = 1 + 4 * u;
        STEP(s0 + 0, f0, 0); STEP(s0 + 1, f1, 0);
        STEP(s0 + 2, f2, 0); STEP(s0 + 3, f3, 0);
    }
    #pragma unroll 1
    for (int u = 16; u < 64; ++u) {         // s in [65,256]: steady, all active
        const int f0 = __builtin_amdgcn_readlane(tok_store.x, u);
        const int f1 = __builtin_amdgcn_readlane(tok_store.y, u);
        const int f2 = __builtin_amdgcn_readlane(tok_store.z, u);
        const int f3 = __builtin_amdgcn_readlane(tok_store.w, u);
        const int s0 = 1 + 4 * u;
        STEP(s0 + 0, f0, 1); STEP(s0 + 1, f1, 1);
        STEP(s0 + 2, f2, 1); STEP(s0 + 3, f3, 1);
    }
    #pragma unroll 1
    for (int u = 64; u < 80; ++u) {         // s in [257,320]: drain
        const int s0 = 1 + 4 * u;
        STEP(s0 + 0, 0, 2); STEP(s0 + 1, 0, 2);
        STEP(s0 + 2, 0, 2); STEP(s0 + 3, 0, 2);
    }

    const float fin = lse3(cM2 + aKM2M, cI2 + aKI2M, cD2 + aKD2M);
    if (i == 63) nll_out[b] = -fin * LN2;
}

__global__ __launch_bounds__(256) void phmm_finish(const float* __restrict__ nll,
                                                   const float* __restrict__ mus,
                                                   const float* __restrict__ logvars,
                                                   float* __restrict__ out)
{
    const int tid = threadIdx.x;
    float acc = 0.0f;
    for (int idx = tid; idx < 512; idx += 256) acc += nll[idx];
    for (int idx = tid; idx < 8192; idx += 256) {
        const float mu = mus[idx], lv = logvars[idx];
        acc -= 0.5f * (1.0f + lv - mu * mu - exp2_hw(lv * LOG2E));
    }
    #pragma unroll
    for (int off = 32; off >= 1; off >>= 1) acc += __shfl_down(acc, off);
    __shared__ float red[4];
    if ((tid & 63) == 0) red[tid >> 6] = acc;
    __syncthreads();
    if (tid == 0) out[0] = (red[0] + red[1] + red[2] + red[3]) * (1.0f / 512.0f);
}

extern "C" void kernel_launch(void* const* d_in, const int* in_sizes, int n_in,
                              void* d_out, int out_size, void* d_ws, size_t ws_size,
                              hipStream_t stream)
{
    const int*   tokens  = (const int*)d_in[0];   // (512, 256) int32
    const float* trans   = (const float*)d_in[1]; // (512, 129, 7) f32
    const float* emis    = (const float*)d_in[2]; // (512, 128, 4) f32
    const float* mus     = (const float*)d_in[3]; // (512, 16) f32
    const float* logvars = (const float*)d_in[4]; // (512, 16) f32
    float* nll = (float*)d_ws;                    // 512 floats scratch

    phmm_fwd<<<dim3(512), dim3(64), 0, stream>>>(tokens, trans, emis, nll);
    phmm_finish<<<dim3(1), dim3(256), 0, stream>>>(nll, mus, logvars, (float*)d_out);
}